// Round 7
// baseline (177.979 us; speedup 1.0000x reference)
//
#include <hip/hip_runtime.h>
#include <hip/hip_bf16.h>

#define B_N 32
#define C_K 512
#define T_N 1024
#define D_M 512

constexpr int BM = 128, BN = 128, BK = 32;
constexpr int SA = 40;            // shorts per LDS row (80B): minimal 16B-aligned
                                  // row that ROTATES banks (5 slots/row, 5⊥8)
constexpr int KSTEPS = C_K / BK;  // 16

typedef __attribute__((ext_vector_type(4))) float  floatx4;
typedef __attribute__((ext_vector_type(8))) short  shortx8;
typedef __attribute__((ext_vector_type(4))) unsigned int uintx4;

__device__ __forceinline__ unsigned pk2(float a, float b) {
  __hip_bfloat162 h = __float22bfloat162_rn(make_float2(a, b));
  union { __hip_bfloat162 v; unsigned u; } c; c.v = h; return c.u;
}

// out[b,d,t] = sum_c x[b,c,t] * W[sub[b],c,d] + bias[sub[b],d]
// Per-b GEMM: A = W[nb] (K x M, m-contig), B = X[b] (K x N, n-contig)
//
// LDS (round 7): [row][k] bf16, SA=40 shorts (80B rows: 64B data + 16B pad).
// Rationale: round-6's 64B rows span the banks exactly once, so the row index
// cancels out of the bank-slot -> staging ds_write_b128 was stuck at 16
// lanes/slot = 2x floor (8.39M conflict cy), and LDS is now ~67% of the
// step wall (32KB reads + 2x16KB writes vs 128B/cy). 80B rows rotate 5
// slots/row (5 coprime 8). Swizzle on 16B k-chunks: phys_q = q ^ ((row>>4)&3).
//   Writes (R=4mg+r): slot16 = (4mg+5r+(oct^sw)) mod 8 -> 8 lanes/slot = FLOOR.
//   Reads (R=wm+16i+l15): slot16 = (5*l15+(q^i)) mod 8 + const -> 8/slot = FLOOR.
// Cost: LDS 40,960B/block; 3 blocks = 122,880 <= pool (round 3 proved pool
// >= 110,592; round 6 refusal only proved < 131,072).
//
// Pipeline: depth-1, __syncthreads. Depth-2 register prefetch is structurally
// dead (round 5: spills, WRITE 65->294MB). Occupancy levers dead (rounds 4,6:
// stuck at 3 blocks/CU regardless). Within-step overlap only.
__global__ __launch_bounds__(256, 3)
void subject_gemm(const float* __restrict__ x, const int* __restrict__ subjects,
                  const float* __restrict__ weights, const float* __restrict__ bias,
                  float* __restrict__ out)
{
  __shared__ __align__(16) short lds_a[2][BM * SA]; // [m][k] bf16 (chunk16-swizzled)
  __shared__ __align__(16) short lds_b[2][BN * SA]; // [n][k]

  // XCD-aware swizzle: all 32 tiles of a batch land on one XCD.
  const int bid  = blockIdx.x;
  const int xcd  = bid & 7;
  const int s    = bid >> 3;           // 0..127
  const int b    = xcd * 4 + (s & 3);  // 4 batches per XCD
  const int tile = s >> 2;             // 0..31
  const int tm = tile >> 3, tn = tile & 7;
  const int m0 = tm * BM, n0 = tn * BN;
  const int nb = subjects[b];

  const float* __restrict__ Wp = weights + (size_t)nb * C_K * D_M; // [k][m]
  const float* __restrict__ Xp = x + (size_t)b * C_K * T_N;        // [k][n]

  const int tid  = threadIdx.x;
  const int lane = tid & 63;
  const int wave = tid >> 6;

  // ---- staging role: waves 0-1 stage A, waves 2-3 stage B ----
  const bool isA = (wave < 2);
  const int  mg  = (wave & 1) * 16 + (lane & 15); // rows 4*mg..4*mg+3
  const int  oct = lane >> 4;                     // k-chunk16; k = 8*oct + jj
  const float* gsrc = isA ? (Wp + (size_t)(8 * oct) * D_M + (m0 + 4 * mg))
                          : (Xp + (size_t)(8 * oct) * T_N + (n0 + 4 * mg));
  const int gs = isA ? D_M : T_N;
  const int sw   = (mg >> 2) & 3;                 // s(row)=(row>>4)&3 for rows 4mg..4mg+3
  const int cOff = 8 * (oct ^ sw);                // short offset of phys chunk16
  short* const wbase = (isA ? &lds_a[0][0] : &lds_b[0][0]) + (4 * mg) * SA + cOff;
  constexpr int BUFO = BM * SA;

  // ---- compute role: 4 waves, 64x64 tiles ----
  const int wm = (wave & 1) * 64, wn = (wave >> 1) * 64;
  const int l15 = lane & 15, q = lane >> 4;

  floatx4 acc[4][4] = {};
  floatx4 v[8];

  // ---- prologue: load+stage tile 0 into buf 0 ----
  #pragma unroll
  for (int jj = 0; jj < 8; ++jj)
    v[jj] = *(const floatx4*)(gsrc + (size_t)jj * gs);
  gsrc += (size_t)BK * gs;
  #pragma unroll
  for (int r = 0; r < 4; ++r) {
    uintx4 pk = { pk2(v[0][r], v[1][r]), pk2(v[2][r], v[3][r]),
                  pk2(v[4][r], v[5][r]), pk2(v[6][r], v[7][r]) };
    *(uintx4*)(wbase + r * SA) = pk;
  }

  for (int ks = 0; ks < KSTEPS; ++ks) {
    const int p = ks & 1;
    __syncthreads(); // buf p ready; drains vmem (nothing outstanding here)

    // issue next tile's loads AFTER the barrier so they stay in flight
    // across frag reads + MFMA (vmcnt wait lands at the cvt block below)
    if (ks + 1 < KSTEPS) {
      #pragma unroll
      for (int jj = 0; jj < 8; ++jj)
        v[jj] = *(const floatx4*)(gsrc + (size_t)jj * gs);
      gsrc += (size_t)BK * gs;
    }

    // fragments from buf p: single b128 each, phys chunk = q ^ i (wave-uniform)
    const short* pa = &lds_a[p][0] + (wm + l15) * SA;
    const short* pb = &lds_b[p][0] + (wn + l15) * SA;
    shortx8 af[4], bg[4];
    #pragma unroll
    for (int i = 0; i < 4; ++i) {
      af[i] = *(const shortx8*)(pa + 16 * i * SA + 8 * (q ^ i));
      bg[i] = *(const shortx8*)(pb + 16 * i * SA + 8 * (q ^ i));
    }
    #pragma unroll
    for (int i = 0; i < 4; ++i)
      #pragma unroll
      for (int j = 0; j < 4; ++j)
        acc[i][j] = __builtin_amdgcn_mfma_f32_16x16x32_bf16(af[i], bg[j], acc[i][j], 0, 0, 0);

    // cvt (vmcnt wait lands HERE, after MFMA) + stage into buf p^1
    if (ks + 1 < KSTEPS) {
      short* wdst = wbase + (p ^ 1) * BUFO;
      #pragma unroll
      for (int r = 0; r < 4; ++r) {
        uintx4 pk = { pk2(v[0][r], v[1][r]), pk2(v[2][r], v[3][r]),
                      pk2(v[4][r], v[5][r]), pk2(v[6][r], v[7][r]) };
        *(uintx4*)(wdst + r * SA) = pk;
      }
    }
  }

  // ---- epilogue: col = lane&15 (t), row = 4q + r (d) ----
  float* __restrict__ O = out + (size_t)b * D_M * T_N;
  const float* __restrict__ bb = bias + (size_t)nb * D_M;
  #pragma unroll
  for (int i = 0; i < 4; ++i) {
    #pragma unroll
    for (int r = 0; r < 4; ++r) {
      const int d = m0 + wm + 16 * i + 4 * q + r;
      const float bv = bb[d];
      #pragma unroll
      for (int j = 0; j < 4; ++j) {
        const int t = n0 + wn + 16 * j + l15;
        O[(size_t)d * T_N + t] = acc[i][j][r] + bv;
      }
    }
  }
}

extern "C" void kernel_launch(void* const* d_in, const int* in_sizes, int n_in,
                              void* d_out, int out_size, void* d_ws, size_t ws_size,
                              hipStream_t stream) {
  const float* x        = (const float*)d_in[0];
  const int*   subjects = (const int*)d_in[1];
  const float* weights  = (const float*)d_in[2];
  const float* bias     = (const float*)d_in[3];
  float* out = (float*)d_out;
  (void)in_sizes; (void)n_in; (void)out_size; (void)d_ws; (void)ws_size;

  dim3 grid(B_N * 4 * 8); // 1024 blocks: 32 b x 4 tm x 8 tn
  dim3 block(256);
  hipLaunchKernelGGL(subject_gemm, grid, block, 0, stream, x, subjects, weights, bias, out);
}